// Round 1
// 160.110 us; speedup vs baseline: 1.0102x; 1.0102x over previous
//
#include <hip/hip_runtime.h>
#include <hip/hip_bf16.h>
#include <math.h>

#define BB 2
#define NN 65000
#define MM 64
#define DIM 192
#define NH 4
#define HD 48
#define GS 128
#define NG 508            // ceil(65000/128)
#define SORT_TPB 256
#define NBLK 254          // ceil(65000/256)

#define NROWS_PAD 130048  // BB*NN padded to 64-row tiles
#define NROWTILES 2032    // 130048/64

typedef __attribute__((ext_vector_type(8))) short bf16x8;
typedef __attribute__((ext_vector_type(8))) _Float16 f16x8;
typedef __attribute__((ext_vector_type(2))) __fp16 fp16x2;
typedef __attribute__((ext_vector_type(4))) float f32x4;
typedef __attribute__((ext_vector_type(16))) float f32x16;
typedef __attribute__((ext_vector_type(8))) unsigned short u16x8;

__device__ __forceinline__ unsigned short f2bf(float f) {
  __hip_bfloat16 h = __float2bfloat16(f);
  return *(unsigned short*)&h;
}
// pack two f32 -> two f16 in one uint (v_cvt_pkrtz_f16_f32)
__device__ __forceinline__ unsigned int pkh(float lo, float hi) {
  fp16x2 t = __builtin_amdgcn_cvt_pkrtz(lo, hi);
  return *(unsigned int*)&t;
}
__device__ __forceinline__ f16x8 cvt8h(float4 a, float4 b) {
  f16x8 r;
  r[0] = (_Float16)a.x; r[1] = (_Float16)a.y; r[2] = (_Float16)a.z; r[3] = (_Float16)a.w;
  r[4] = (_Float16)b.x; r[5] = (_Float16)b.y; r[6] = (_Float16)b.z; r[7] = (_Float16)b.w;
  return r;
}
// async global->LDS, 16B per lane; dest = lds_base + lane*16 (linear)
__device__ __forceinline__ void gload_lds16(const float* src, float* lds_dst) {
  __builtin_amdgcn_global_load_lds(
      (const __attribute__((address_space(1))) unsigned int*)src,
      (__attribute__((address_space(3))) unsigned int*)lds_dst, 16, 0, 0);
}

// ---------------- K1: fused per-token argmax + per-block histogram --------
__global__ void k_argmax_hist(const float* __restrict__ sim, int* __restrict__ tk,
                              int* __restrict__ hist) {
  __shared__ int cnt[MM];
  const int b = blockIdx.y, blk = blockIdx.x;
  if (threadIdx.x < MM) cnt[threadIdx.x] = 0;
  __syncthreads();
  int t = blk * SORT_TPB + threadIdx.x;
  if (t < NN) {
    const float4* row = (const float4*)(sim + ((size_t)b * NN + t) * MM);
    float best = -INFINITY;
    int bi = 0;
#pragma unroll
    for (int j = 0; j < MM / 4; ++j) {
      float4 v = row[j];
      if (v.x > best) { best = v.x; bi = 4 * j + 0; }
      if (v.y > best) { best = v.y; bi = 4 * j + 1; }
      if (v.z > best) { best = v.z; bi = 4 * j + 2; }
      if (v.w > best) { best = v.w; bi = 4 * j + 3; }
    }
    tk[b * NN + t] = bi;
    atomicAdd(&cnt[bi], 1);
  }
  __syncthreads();
  if (threadIdx.x < MM)
    hist[(b * NBLK + blk) * MM + threadIdx.x] = cnt[threadIdx.x];
}

// ---------------- K3: scan (256 threads: 4 segments x 64 bins) ------------
__global__ void k_scan(const int* __restrict__ hist, int* __restrict__ boff) {
  const int b = blockIdx.x;
  const int tid = threadIdx.x;
  const int seg = tid >> 6, bin = tid & 63;
  __shared__ int part[4][MM];
  __shared__ int basev[MM];
  const int lo = seg * 64, hi = (seg == 3) ? NBLK : (lo + 64);
  int s = 0;
  for (int blk = lo; blk < hi; ++blk) s += hist[(b * NBLK + blk) * MM + bin];
  part[seg][bin] = s;
  __syncthreads();
  if (tid < 64) {
    int tot = part[0][bin] + part[1][bin] + part[2][bin] + part[3][bin];
    int incl = tot;
#pragma unroll
    for (int d = 1; d < 64; d <<= 1) {
      int o = __shfl_up(incl, d);
      if (bin >= d) incl += o;
    }
    basev[bin] = incl - tot;   // exclusive prefix over bins
  }
  __syncthreads();
  int run = basev[bin];
  for (int s2 = 0; s2 < seg; ++s2) run += part[s2][bin];
  for (int blk = lo; blk < hi; ++blk) {
    int h = hist[(b * NBLK + blk) * MM + bin];
    boff[(b * NBLK + blk) * MM + bin] = run;
    run += h;
  }
}

// ---------------- K4: stable scatter → sort_idx (ballot rank) -------------
// rank within wave = popc(same-bin mask & lanes-below); 6 ballots since bin
// is 6-bit. Cross-wave prefix via per-wave bin counts in LDS. Ordering is
// identical to the old serial loop (lane order == tid order) so the sort is
// bitwise-identical.
// Invalid lanes (t>=NN, only last block, highest lanes) alias bin 63 in the
// ballot mask; they sit ABOVE every valid lane so valid ranks are unaffected,
// and the inflated count lands in whist[3][...] which is never consumed.
__global__ void k_scatter(const int* __restrict__ tk, const int* __restrict__ boff,
                          int* __restrict__ sidx) {
  __shared__ int whist[4][MM];
  const int b = blockIdx.y, blk = blockIdx.x;
  const int tid = threadIdx.x;
  const int w = tid >> 6, lane = tid & 63;
  ((int*)whist)[tid] = 0;   // 256 == 4*MM
  __syncthreads();
  int t = blk * SORT_TPB + tid;
  int bin = (t < NN) ? tk[b * NN + t] : -1;
  unsigned long long m = ~0ull;
#pragma unroll
  for (int bit = 0; bit < 6; ++bit) {
    unsigned long long bl = __ballot((bin >> bit) & 1);
    m &= ((bin >> bit) & 1) ? bl : ~bl;
  }
  int rank_w = __popcll(m & ((1ull << lane) - 1ull));
  if (bin >= 0 && rank_w == 0) whist[w][bin] = __popcll(m);
  __syncthreads();
  if (bin >= 0) {
    int rank = rank_w;
#pragma unroll
    for (int w2 = 0; w2 < 3; ++w2)
      if (w2 < w) rank += whist[w2][bin];
    int pos = boff[(b * NBLK + blk) * MM + bin] + rank;
    sidx[b * NN + pos] = t;
  }
}

// ---------------- K5: MFMA group attention (fp16 internals) ---------------
// Block = 256 threads = 4 waves, one (b,g,head). Wave w owns q-cols [32w,32w+32).
// QK^T: A=K (row=kv), B=Q (col=q)  -> lane holds P[kv...] for q = 32w+(lane&31).
// Softmax: in-lane over 64 regs + one shfl_xor(32).
// PV:  A=P (pkrtz-pair + lane^32 exchange), B=V-frags.
// V staged via async global_load_lds (fp32, linear LDS), cvt in repack (RNE,
// numerics identical to r5). K reg-staged directly in A-frag order.
__global__ __launch_bounds__(256) void k_attn_mfma(const float* __restrict__ qkv,
                                                   const int* __restrict__ sidx,
                                                   const float* __restrict__ logit_scale,
                                                   __hip_bfloat16* __restrict__ attn_out) {
  const int x = blockIdx.x;                 // 2048 slots: g=(x>>5)*8+(x&7), hd=(x>>3)&3
  const int g = ((x >> 5) << 3) + (x & 7);  // 4 heads of a group: 8 apart -> same XCD
  const int hd = (x >> 3) & 3;
  const int b = blockIdx.z;
  if (g >= NG) return;

  __shared__ int stok[GS];
  __shared__ _Float16 akv[4 * 3 * 64 * 8];    // K A-frags, lane-linear (12 KB)
  __shared__ float vrowf[GS][HD];             // V row-major fp32 (24 KB, gload_lds)
  __shared__ _Float16 vfrag[2 * 8 * 64 * 8];  // V B-frags (16 KB, d>=48 zero)

  const int tid = threadIdx.x;
  const int w = tid >> 6, l = tid & 63;
  const int hl = l >> 5, l31 = l & 31;

  if (tid < GS) {
    int s = g * GS + tid;
    int sp = (s < NN) ? s : (2 * NN - 1 - s);   // reflect padding
    stok[tid] = sidx[b * NN + sp];
  }
  __syncthreads();

  // --- V: async global->LDS, per-lane scattered source, linear dest ---
  // chunk c (16B) -> vrowf byte c*16: row=c/12, piece=c%12 (192B/row)
#pragma unroll
  for (int i = 0; i < 6; ++i) {
    int c = (i * 4 + w) * 64 + l;
    int row = c / 12, piece = c % 12;
    const float* src = qkv + (size_t)(b * NN + stok[row]) * (3 * DIM) + 2 * DIM + hd * HD + piece * 4;
    gload_lds16(src, &vrowf[0][0] + (i * 4 + w) * 256);
  }

  // --- Q B-frags: per-lane direct global load (no LDS) ---
  f16x8 qf[3];
  {
    const float* qsrc = qkv + (size_t)(b * NN + stok[w * 32 + l31]) * (3 * DIM) + hd * HD;
#pragma unroll
    for (int s = 0; s < 3; ++s) {
      const float4* p = (const float4*)(qsrc + s * 16 + hl * 8);
      qf[s] = cvt8h(p[0], p[1]);
    }
  }

  // --- K A-frags: stage directly in fragment order (lane-linear 16B) ---
#pragma unroll
  for (int i = 0; i < 3; ++i) {
    int c = tid + 256 * i;                   // 0..767 = (t*3+s)*64 + lane
    int ts = c >> 6, cl = c & 63;
    int kvr = (ts / 3) * 32 + (cl & 31);
    int dbase = (ts % 3) * 16 + (cl >> 5) * 8;
    const float* src = qkv + (size_t)(b * NN + stok[kvr]) * (3 * DIM) + DIM + hd * HD + dbase;
    ((f16x8*)akv)[c] = cvt8h(((const float4*)src)[0], ((const float4*)src)[1]);
  }
  __syncthreads();   // drains gload_lds (vmcnt) + akv writes

  // --- V repack -> B-frags (fp32 column reads: bank=(l31+row*48)%32, CF) ---
#pragma unroll
  for (int i = 0; i < 4; ++i) {
    int c = tid + 256 * i;                   // (nt*8+ks)*64 + lane
    int ntks = c >> 6, cl = c & 63;
    int nt = ntks >> 3, ks = ntks & 7;
    int d = nt * 32 + (cl & 31);
    int kvb = ks * 16 + (cl >> 5) * 8;
    _Float16 tmp[8];
#pragma unroll
    for (int e = 0; e < 8; ++e) tmp[e] = (d < HD) ? (_Float16)vrowf[kvb + e][d] : (_Float16)0.f;
    ((f16x8*)vfrag)[c] = *(f16x8*)tmp;
  }
  __syncthreads();

  // --- QK^T: 4 kv-tiles x 3 d-steps ---
  f32x16 accS[4];
#pragma unroll
  for (int t = 0; t < 4; ++t)
#pragma unroll
    for (int r = 0; r < 16; ++r) accS[t][r] = 0.f;

#pragma unroll
  for (int t = 0; t < 4; ++t)
#pragma unroll
    for (int s = 0; s < 3; ++s) {
      f16x8 af = ((const f16x8*)akv)[(t * 3 + s) * 64 + l];
      accS[t] = __builtin_amdgcn_mfma_f32_32x32x16_f16(af, qf[s], accS[t], 0, 0, 0);
    }

  // --- softmax (each lane: full row for q=32w+l31, split with lane^32) ---
  const float scale = expf(fminf(logit_scale[0], 4.6051701860f));
  float mx = -INFINITY;
#pragma unroll
  for (int t = 0; t < 4; ++t)
#pragma unroll
    for (int r = 0; r < 16; ++r) { accS[t][r] *= scale; mx = fmaxf(mx, accS[t][r]); }
  mx = fmaxf(mx, __shfl_xor(mx, 32));
  float sum = 0.f;
#pragma unroll
  for (int t = 0; t < 4; ++t)
#pragma unroll
    for (int r = 0; r < 16; ++r) { float p = __expf(accS[t][r] - mx); accS[t][r] = p; sum += p; }
  sum += __shfl_xor(sum, 32);
  const float inv = 1.f / sum;
#pragma unroll
  for (int t = 0; t < 4; ++t)
#pragma unroll
    for (int r = 0; r < 16; ++r) accS[t][r] *= inv;

  // --- PV: build P A-frags in-register, 2 d-tiles x 8 k-steps ---
  f32x16 accO[2];
#pragma unroll
  for (int nt = 0; nt < 2; ++nt)
#pragma unroll
    for (int r = 0; r < 16; ++r) accO[nt][r] = 0.f;

#pragma unroll
  for (int t = 0; t < 4; ++t) {
    union { unsigned int u[4]; f16x8 v; } fa, fb;
    {
      unsigned int a0 = pkh(accS[t][0], accS[t][1]);
      unsigned int a1 = pkh(accS[t][2], accS[t][3]);
      unsigned int b0 = pkh(accS[t][4], accS[t][5]);
      unsigned int b1 = pkh(accS[t][6], accS[t][7]);
      unsigned int sa0 = __shfl_xor(a0, 32), sa1 = __shfl_xor(a1, 32);
      unsigned int sb0 = __shfl_xor(b0, 32), sb1 = __shfl_xor(b1, 32);
      fa.u[0] = hl ? sb0 : a0; fa.u[1] = hl ? sb1 : a1;
      fa.u[2] = hl ? b0 : sa0; fa.u[3] = hl ? b1 : sa1;
    }
    {
      unsigned int a0 = pkh(accS[t][8], accS[t][9]);
      unsigned int a1 = pkh(accS[t][10], accS[t][11]);
      unsigned int b0 = pkh(accS[t][12], accS[t][13]);
      unsigned int b1 = pkh(accS[t][14], accS[t][15]);
      unsigned int sa0 = __shfl_xor(a0, 32), sa1 = __shfl_xor(a1, 32);
      unsigned int sb0 = __shfl_xor(b0, 32), sb1 = __shfl_xor(b1, 32);
      fb.u[0] = hl ? sb0 : a0; fb.u[1] = hl ? sb1 : a1;
      fb.u[2] = hl ? b0 : sa0; fb.u[3] = hl ? b1 : sa1;
    }
    accO[0] = __builtin_amdgcn_mfma_f32_32x32x16_f16(fa.v, ((const f16x8*)vfrag)[(0 * 8 + 2 * t) * 64 + l], accO[0], 0, 0, 0);
    accO[1] = __builtin_amdgcn_mfma_f32_32x32x16_f16(fa.v, ((const f16x8*)vfrag)[(1 * 8 + 2 * t) * 64 + l], accO[1], 0, 0, 0);
    accO[0] = __builtin_amdgcn_mfma_f32_32x32x16_f16(fb.v, ((const f16x8*)vfrag)[(0 * 8 + 2 * t + 1) * 64 + l], accO[0], 0, 0, 0);
    accO[1] = __builtin_amdgcn_mfma_f32_32x32x16_f16(fb.v, ((const f16x8*)vfrag)[(1 * 8 + 2 * t + 1) * 64 + l], accO[1], 0, 0, 0);
  }

  // --- store to ORIGINAL token position, bf16 ---
#pragma unroll
  for (int r = 0; r < 16; ++r) {
    int rowl = w * 32 + (r & 3) + 8 * (r >> 2) + 4 * hl;
    int sg = g * GS + rowl;
    if (sg < NN) {
      size_t base = (size_t)(b * NN + stok[rowl]) * DIM + hd * HD;
      attn_out[base + l31] = __float2bfloat16(accO[0][r]);
      if (l31 < 16) attn_out[base + 32 + l31] = __float2bfloat16(accO[1][r]);
    }
  }
}

// ---------------- K6a: pack W into MFMA B-fragment order ------------------
__global__ void k_wpack(const float* __restrict__ W, unsigned short* __restrict__ wpack) {
  int idx = blockIdx.x * blockDim.x + threadIdx.x;
  if (idx >= 12 * 6 * 64) return;
  int lane = idx & 63;
  int kkjt = idx >> 6;
  int kk = kkjt % 6;
  int jt = kkjt / 6;
  int j = jt * 16 + (lane & 15);
  int k0 = kk * 32 + (lane >> 4) * 8;
  const float* src = W + (size_t)j * DIM + k0;
  unsigned short tmp[8];
#pragma unroll
  for (int e = 0; e < 8; ++e) tmp[e] = f2bf(src[e]);
  ((u16x8*)wpack)[idx] = *(const u16x8*)tmp;
}

// ---------------- K6b: projection via bf16 MFMA (full 192-wide) -----------
// One block now computes ALL 12 output col-tiles per row-tile, so each A row
// (x_bf16) is read exactly once (was: read twice by the jhalf split).
// wl = 72 KB LDS (fits gfx950's 160 KB; 2 blocks/CU), staged async.
__global__ __launch_bounds__(256) void k_proj_mfma(const unsigned short* __restrict__ xb,
                                                   const unsigned short* __restrict__ wpack,
                                                   const float* __restrict__ bias,
                                                   float* __restrict__ out) {
  __shared__ unsigned short wl[12 * 6 * 64 * 8];   // 72 KB
  const int tid = threadIdx.x;

  // async stage: chunk c dest = base + (j*256 + w*64)*16 + lane*16 (linear per wave)
#pragma unroll
  for (int j = 0; j < 18; ++j) {
    int c = j * 256 + tid;
    gload_lds16((const float*)((const u16x8*)wpack + c), (float*)((u16x8*)wl + c));
  }

  const int wid = tid >> 6, lane = tid & 63;
  const int l15 = lane & 15, lk = lane >> 4;

  float bv[12];
#pragma unroll
  for (int jt = 0; jt < 12; ++jt) bv[jt] = bias[jt * 16 + l15];

  __syncthreads();   // drains gload_lds vmcnt

  for (int tile = blockIdx.x; tile < NROWTILES; tile += gridDim.x) {
    const int r0 = tile * 64 + wid * 16;
    f32x4 acc[12];
#pragma unroll
    for (int jt = 0; jt < 12; ++jt) { f32x4 t = {bv[jt], bv[jt], bv[jt], bv[jt]}; acc[jt] = t; }

    const unsigned short* xrow = xb + (size_t)(r0 + l15) * DIM;
#pragma unroll
    for (int kk = 0; kk < 6; ++kk) {
      bf16x8 a = *(const bf16x8*)(xrow + kk * 32 + lk * 8);
#pragma unroll
      for (int jt = 0; jt < 12; ++jt) {
        bf16x8 b = *(const bf16x8*)(wl + ((jt * 6 + kk) * 64 + lane) * 8);
        acc[jt] = __builtin_amdgcn_mfma_f32_16x16x32_bf16(a, b, acc[jt], 0, 0, 0);
      }
    }

    const int rowb = r0 + lk * 4;
#pragma unroll
    for (int jt = 0; jt < 12; ++jt) {
#pragma unroll
      for (int r = 0; r < 4; ++r) {
        int row = rowb + r;
        if (row < BB * NN)
          out[(size_t)row * DIM + jt * 16 + l15] = acc[jt][r];
      }
    }
  }
}

// ---------------- launch --------------------------------------------------
extern "C" void kernel_launch(void* const* d_in, const int* in_sizes, int n_in,
                              void* d_out, int out_size, void* d_ws, size_t ws_size,
                              hipStream_t stream) {
  const float* qkv = (const float*)d_in[0];
  const float* sim = (const float*)d_in[1];
  const float* proj_w = (const float*)d_in[2];
  const float* proj_b = (const float*)d_in[3];
  const float* logit_scale = (const float*)d_in[4];

  unsigned short* x_bf16 = (unsigned short*)d_ws;                 // NROWS_PAD*DIM bf16
  unsigned short* wpack = x_bf16 + (size_t)NROWS_PAD * DIM;       // 12*6*64*8
  int* tk = (int*)(wpack + 12 * 6 * 64 * 8);                      // BB*NN
  int* hist = tk + (size_t)BB * NN;                               // BB*NBLK*MM
  int* boff = hist + (size_t)BB * NBLK * MM;                      // BB*NBLK*MM
  int* sidx = boff + (size_t)BB * NBLK * MM;                      // BB*NN

  k_argmax_hist<<<dim3(NBLK, BB), SORT_TPB, 0, stream>>>(sim, tk, hist);
  k_scan<<<BB, 256, 0, stream>>>(hist, boff);
  k_scatter<<<dim3(NBLK, BB), SORT_TPB, 0, stream>>>(tk, boff, sidx);
  k_wpack<<<(12 * 6 * 64 + 255) / 256, 256, 0, stream>>>(proj_w, wpack);
  k_attn_mfma<<<dim3(2048, 1, BB), 256, 0, stream>>>(qkv, sidx, logit_scale,
                                                     (__hip_bfloat16*)x_bf16);
  k_proj_mfma<<<dim3(1016), 256, 0, stream>>>(x_bf16, wpack, proj_b, (float*)d_out);
}